// Round 4
// baseline (274.032 us; speedup 1.0000x reference)
//
#include <hip/hip_runtime.h>
#include <stdint.h>

// Problem constants
#define BT     32768      // B*T rows
#define CIN    512
#define NE     640        // GROUP*ENTRY
#define ENTRY  320
#define DD     256        // COUT/GROUP
#define MROWS  32         // rows per block
#define TPB    256        // 4 waves

using bf16x8 = __attribute__((ext_vector_type(8))) short;
using f32x4  = __attribute__((ext_vector_type(4))) float;

// LDS layout (bytes):
//   A  bf16 [32 rows][512], XOR-swizzled : [0, 32768)   phase 0/1
//   y  bf16 [32 rows][640], XOR-swizzled : [0, 40960)   phase 2/3 (unions A)
//   S  f32 [32]                          : [40960, 41088)
// 41.1 KB/block -> 3 blocks/CU LDS-wise; occupancy bet is the register cap.
#define S_OFF      40960
#define SMEM_BYTES 41088

__device__ __forceinline__ unsigned short f2b(float f) {
    union { float f; uint32_t u; } v; v.f = f;
    uint32_t u = v.u;
    return (unsigned short)((u + 0x7FFFu + ((u >> 16) & 1u)) >> 16);
}

// Prep into MFMA-fragment order:
//   WpB2 [ks][e][kk]  : ks 0..15 (k0=ks*32), e 0..639, kk 0..31
//       WpB2[ks*20480 + e*32 + kk] = bf16(Wp[e][ks*32+kk])
//   cbT2 [g][ks][n][kk]: ks 0..9, n 0..255, kk 0..31
//       cbT2[((g*10+ks)*256 + n)*32 + kk] = bf16(cb[g][ks*32+kk][n])
// A wave's B-fragment load (64 lanes x 16B) is then one contiguous 1KB span.
__global__ void prep_kernel(const float* __restrict__ Wp, const float* __restrict__ cb,
                            unsigned short* __restrict__ WpB2, unsigned short* __restrict__ cbT2) {
    int i = blockIdx.x * blockDim.x + threadIdx.x;
    if (i < NE * CIN) {
        int ks  = i / 20480;
        int rem = i - ks * 20480;
        int e   = rem >> 5;
        int kk  = rem & 31;
        WpB2[i] = f2b(Wp[e * CIN + ks * 32 + kk]);
    } else {
        int o = i - NE * CIN;
        if (o < 2 * ENTRY * DD) {
            int kk = o & 31;
            int t  = o >> 5;
            int n  = t & 255;
            int t2 = t >> 8;
            int ks = t2 % 10;
            int g  = t2 / 10;
            cbT2[o] = f2b(cb[(g * ENTRY + ks * 32 + kk) * DD + n]);
        }
    }
}

__global__ __launch_bounds__(TPB, 3) void fused_kernel(
    const float* __restrict__ x, const float* __restrict__ bp,
    const float* __restrict__ gum, const unsigned short* __restrict__ WpB2,
    const unsigned short* __restrict__ cbT2, float* __restrict__ out) {

    extern __shared__ char smem[];
    float* sS = (float*)(smem + S_OFF);

    const int tid = threadIdx.x;
    const int w  = tid >> 6;     // wave 0..3
    const int l  = tid & 63;
    const int q  = l >> 4;       // quad 0..3
    const int ln = l & 15;
    const int rowbase = blockIdx.x * MROWS;
    const int swz = (ln & 7) << 4;

    if (tid < MROWS) sS[tid] = 0.0f;

    // ---------------- Phase 0: stage x -> bf16 LDS (once, swizzled) ----------------
    {
        const int ar  = tid >> 3;   // row 0..31
        const int akq = tid & 7;    // 4-float quarter within 32-elem chunk
        const float* xrow = x + (size_t)(rowbase + ar) * CIN + akq * 4;
        const int abase = ar * 1024;
        const int aswz  = (ar & 7) << 4;
#pragma unroll
        for (int c = 0; c < 16; ++c) {
            float4 xv = *(const float4*)(xrow + c * 32);
            ushort4 hv;
            hv.x = f2b(xv.x); hv.y = f2b(xv.y); hv.z = f2b(xv.z); hv.w = f2b(xv.w);
            *(ushort4*)(smem + abase + ((c * 64 + akq * 8) ^ aswz)) = hv;
        }
    }
    __syncthreads();

    // ---------------- Phase 1: logits = x @ Wp^T (B direct from L2, frag-major) ----------------
    f32x4 acc1[2][10];
    const f32x4 fz = {0.f, 0.f, 0.f, 0.f};
#pragma unroll
    for (int rt = 0; rt < 2; ++rt)
#pragma unroll
        for (int ct = 0; ct < 10; ++ct) acc1[rt][ct] = fz;

    const int blane = ln * 32 + q * 8;   // within a [e][kk] panel slice

#pragma unroll 1
    for (int ks = 0; ks < 16; ++ks) {
        const unsigned short* pk = WpB2 + ks * (NE * 32) + (w * 160) * 32 + blane;
        const int at = (ks * 64 + q * 16) ^ swz;
        bf16x8 af0 = *(const bf16x8*)(smem + ln * 1024 + at);
        bf16x8 af1 = *(const bf16x8*)(smem + ln * 1024 + 16384 + at);
#pragma unroll
        for (int ct = 0; ct < 10; ++ct) {
            bf16x8 bfr = *(const bf16x8*)(pk + ct * 512);   // 16 entries * 32 kk
            acc1[0][ct] = __builtin_amdgcn_mfma_f32_16x16x32_bf16(af0, bfr, acc1[0][ct], 0, 0, 0);
            acc1[1][ct] = __builtin_amdgcn_mfma_f32_16x16x32_bf16(af1, bfr, acc1[1][ct], 0, 0, 0);
        }
    }
    __syncthreads();   // A region dead; y overwrites it

    // ---------------- Phase 2: exp + row sums; y -> LDS (swizzled) ----------------
    float bpv[10];
#pragma unroll
    for (int ct = 0; ct < 10; ++ct) bpv[ct] = bp[w * 160 + ct * 16 + ln];

#pragma unroll
    for (int ri = 0; ri < 8; ++ri) {
        int rt = ri >> 2, r = ri & 3;
        int row = rt * 16 + q * 4 + r;
        const float* pg = gum + (size_t)(rowbase + row) * NE + w * 160 + ln;
        int ybase = row * 1280;
        int yswz  = (row & 7) << 4;
        float p = 0.f;
#pragma unroll
        for (int ct = 0; ct < 10; ++ct) {
            int col = w * 160 + ct * 16 + ln;
            float v = acc1[rt][ct][r] + bpv[ct] + pg[ct * 16];
            float e = __expf(v);
            *(unsigned short*)(smem + ybase + ((col * 2) ^ yswz)) = f2b(e);
            p += e;
        }
        p += __shfl_xor(p, 1);
        p += __shfl_xor(p, 2);
        p += __shfl_xor(p, 4);
        p += __shfl_xor(p, 8);
        if (ln == 0) atomicAdd(&sS[row], p);
    }
    __syncthreads();   // y + S complete before phase 3 reads

    // ---------------- Phase 3: out = (y @ cb) / S (cb direct from L2, frag-major) ----------------
    f32x4 acc2[2][8];
#pragma unroll
    for (int rt = 0; rt < 2; ++rt)
#pragma unroll
        for (int ct = 0; ct < 8; ++ct) acc2[rt][ct] = fz;

    const int g  = w >> 1;          // group
    const int nb = (w & 1) * 128;   // col block within group

#pragma unroll 1
    for (int ks = 0; ks < 10; ++ks) {
        const unsigned short* pk = cbT2 + ((size_t)(g * 10 + ks) * 256 + nb) * 32 + blane;
        const int at = (g * 640 + ks * 64 + q * 16) ^ swz;
        bf16x8 af0 = *(const bf16x8*)(smem + ln * 1280 + at);
        bf16x8 af1 = *(const bf16x8*)(smem + ln * 1280 + 20480 + at);
#pragma unroll
        for (int ct = 0; ct < 8; ++ct) {
            bf16x8 bfr = *(const bf16x8*)(pk + ct * 512);   // 16 cols * 32 kk
            acc2[0][ct] = __builtin_amdgcn_mfma_f32_16x16x32_bf16(af0, bfr, acc2[0][ct], 0, 0, 0);
            acc2[1][ct] = __builtin_amdgcn_mfma_f32_16x16x32_bf16(af1, bfr, acc2[1][ct], 0, 0, 0);
        }
    }

    // epilogue: divide by softmax denom, store fp32
#pragma unroll
    for (int rt = 0; rt < 2; ++rt) {
#pragma unroll
        for (int r = 0; r < 4; ++r) {
            int row = rt * 16 + q * 4 + r;
            float inv = 1.0f / sS[row];
            size_t orow = (size_t)(rowbase + row) * 512;
#pragma unroll
            for (int ct = 0; ct < 8; ++ct) {
                int col = g * 256 + nb + ct * 16 + ln;
                out[orow + col] = acc2[rt][ct][r] * inv;
            }
        }
    }
}

extern "C" void kernel_launch(void* const* d_in, const int* in_sizes, int n_in,
                              void* d_out, int out_size, void* d_ws, size_t ws_size,
                              hipStream_t stream) {
    const float* x   = (const float*)d_in[0];
    const float* Wp  = (const float*)d_in[1];
    const float* bp  = (const float*)d_in[2];
    const float* cb  = (const float*)d_in[3];
    const float* gum = (const float*)d_in[4];
    float* out = (float*)d_out;

    unsigned short* WpB2 = (unsigned short*)d_ws;
    unsigned short* cbT2 = WpB2 + NE * CIN;

    int prep_total = NE * CIN + 2 * ENTRY * DD;
    prep_kernel<<<(prep_total + 255) / 256, 256, 0, stream>>>(Wp, cb, WpB2, cbT2);

    fused_kernel<<<dim3(BT / MROWS), dim3(TPB), SMEM_BYTES, stream>>>(x, bp, gum, WpB2, cbT2, out);
}

// Round 5
// 250.741 us; speedup vs baseline: 1.0929x; 1.0929x over previous
//
#include <hip/hip_runtime.h>
#include <stdint.h>

// Problem constants
#define BT     32768      // B*T rows
#define CIN    512
#define NE     640        // GROUP*ENTRY
#define ENTRY  320
#define DD     256        // COUT/GROUP
#define MROWS  64         // rows per block
#define TPB    512        // 8 waves

using bf16x8 = __attribute__((ext_vector_type(8))) short;
using f32x4  = __attribute__((ext_vector_type(4))) float;

// LDS layout (bytes):
//   A  bf16 [64 rows][512], XOR-swizzled : [0, 65536)   phase 0/1
//   y  bf16 [64 rows][640], XOR-swizzled : [0, 81920)   phase 2/3 (unions A)
//   S  f32 [64]                          : [81920, 82176)
// No B/cb staging: B operands come straight from L2 in MFMA-fragment order.
#define S_OFF      81920
#define SMEM_BYTES 82176

__device__ __forceinline__ unsigned short f2b(float f) {
    union { float f; uint32_t u; } v; v.f = f;
    uint32_t u = v.u;
    return (unsigned short)((u + 0x7FFFu + ((u >> 16) & 1u)) >> 16);
}

// Prep into MFMA-fragment order:
//   WpB2 [ks][e][kk]  : ks 0..15 (k0=ks*32), e 0..639, kk 0..31
//       WpB2[ks*20480 + e*32 + kk] = bf16(Wp[e][ks*32+kk])
//   cbT2 [g][ks][n][kk]: ks 0..9, n 0..255, kk 0..31
//       cbT2[((g*10+ks)*256 + n)*32 + kk] = bf16(cb[g][ks*32+kk][n])
// A wave's B-fragment load (64 lanes x 16B) is one contiguous 1KB span.
__global__ void prep_kernel(const float* __restrict__ Wp, const float* __restrict__ cb,
                            unsigned short* __restrict__ WpB2, unsigned short* __restrict__ cbT2) {
    int i = blockIdx.x * blockDim.x + threadIdx.x;
    if (i < NE * CIN) {
        int ks  = i / 20480;
        int rem = i - ks * 20480;
        int e   = rem >> 5;
        int kk  = rem & 31;
        WpB2[i] = f2b(Wp[e * CIN + ks * 32 + kk]);
    } else {
        int o = i - NE * CIN;
        if (o < 2 * ENTRY * DD) {
            int kk = o & 31;
            int t  = o >> 5;
            int n  = t & 255;
            int t2 = t >> 8;
            int ks = t2 % 10;
            int g  = t2 / 10;
            cbT2[o] = f2b(cb[(g * ENTRY + ks * 32 + kk) * DD + n]);
        }
    }
}

#define MFMA16(d, a, b) d = __builtin_amdgcn_mfma_f32_16x16x32_bf16(a, b, d, 0, 0, 0)

__global__ __launch_bounds__(TPB, 2) void fused_kernel(
    const float* __restrict__ x, const float* __restrict__ bp,
    const float* __restrict__ gum, const unsigned short* __restrict__ WpB2,
    const unsigned short* __restrict__ cbT2, float* __restrict__ out) {

    extern __shared__ char smem[];
    float* sS = (float*)(smem + S_OFF);

    const int tid = threadIdx.x;
    const int w  = tid >> 6;     // wave 0..7
    const int l  = tid & 63;
    const int q  = l >> 4;       // quad 0..3
    const int ln = l & 15;
    const int wr = w >> 2;       // wave-row 0..1 (32 rows each)
    const int wc = w & 3;        // wave-col 0..3
    const int rowbase = blockIdx.x * MROWS;
    const int swz = (ln & 7) << 4;

    if (tid < MROWS) sS[tid] = 0.0f;

    // ---------------- Phase 0: stage x -> bf16 LDS (once, swizzled) ----------------
    {
        const int ar  = tid >> 3;   // row 0..63
        const int akq = tid & 7;
        const float* xrow = x + (size_t)(rowbase + ar) * CIN + akq * 4;
        const int abase = ar * 1024;
        const int aswz  = (ar & 7) << 4;
#pragma unroll
        for (int c = 0; c < 16; ++c) {
            float4 xv = *(const float4*)(xrow + c * 32);
            ushort4 hv;
            hv.x = f2b(xv.x); hv.y = f2b(xv.y); hv.z = f2b(xv.z); hv.w = f2b(xv.w);
            *(ushort4*)(smem + abase + ((c * 64 + akq * 8) ^ aswz)) = hv;
        }
    }
    __syncthreads();

    // ---------------- Phase 1: logits = x @ Wp^T ----------------
    // B direct from L2 (frag-major), hand-unrolled x2 with named prefetch sets so
    // step k+1's 10 global loads + 2 ds_reads fly under step k's 20 MFMAs.
    f32x4 acc1[2][10];
    const f32x4 fz = {0.f, 0.f, 0.f, 0.f};
#pragma unroll
    for (int rt = 0; rt < 2; ++rt)
#pragma unroll
        for (int ct = 0; ct < 10; ++ct) acc1[rt][ct] = fz;

    const int blane = ln * 32 + q * 8;
    const unsigned short* bptr = WpB2 + (wc * 160) * 32 + blane;   // + ks*20480 + ct*512
    const int aB = (wr * 32 + ln) * 1024;                          // + rt*16384

    bf16x8 pA[10], pB[10];
    bf16x8 aA0, aA1, aB0, aB1;
    // prologue: ks=0
#pragma unroll
    for (int ct = 0; ct < 10; ++ct) pA[ct] = *(const bf16x8*)(bptr + ct * 512);
    {
        const int at = (q * 16) ^ swz;
        aA0 = *(const bf16x8*)(smem + aB + at);
        aA1 = *(const bf16x8*)(smem + aB + 16384 + at);
    }

#pragma unroll 1
    for (int ks2 = 0; ks2 < 16; ks2 += 2) {
        // prefetch ks2+1 into the B set
        {
            const unsigned short* pk = bptr + (ks2 + 1) * 20480;
#pragma unroll
            for (int ct = 0; ct < 10; ++ct) pB[ct] = *(const bf16x8*)(pk + ct * 512);
            const int at = ((ks2 + 1) * 64 + q * 16) ^ swz;
            aB0 = *(const bf16x8*)(smem + aB + at);
            aB1 = *(const bf16x8*)(smem + aB + 16384 + at);
        }
#pragma unroll
        for (int ct = 0; ct < 10; ++ct) {
            MFMA16(acc1[0][ct], aA0, pA[ct]);
            MFMA16(acc1[1][ct], aA1, pA[ct]);
        }
        // prefetch ks2+2 into the A set
        if (ks2 + 2 < 16) {
            const unsigned short* pk = bptr + (ks2 + 2) * 20480;
#pragma unroll
            for (int ct = 0; ct < 10; ++ct) pA[ct] = *(const bf16x8*)(pk + ct * 512);
            const int at = ((ks2 + 2) * 64 + q * 16) ^ swz;
            aA0 = *(const bf16x8*)(smem + aB + at);
            aA1 = *(const bf16x8*)(smem + aB + 16384 + at);
        }
#pragma unroll
        for (int ct = 0; ct < 10; ++ct) {
            MFMA16(acc1[0][ct], aB0, pB[ct]);
            MFMA16(acc1[1][ct], aB1, pB[ct]);
        }
    }
    __syncthreads();   // A region dead; y overwrites it

    // Prefetch cb ks=0 fragments now — their L2 latency hides under all of phase 2.
    const int g  = wc >> 1;          // group
    const int nb = (wc & 1) * 128;   // col block within group
    const unsigned short* cptr = cbT2 + (size_t)g * 81920 + nb * 32 + blane;  // + ks*8192 + ct*512
    bf16x8 cA[8], cB[8];
#pragma unroll
    for (int ct = 0; ct < 8; ++ct) cA[ct] = *(const bf16x8*)(cptr + ct * 512);

    // ---------------- Phase 2: exp + row sums; y -> LDS (swizzled) ----------------
    float bpv[10];
#pragma unroll
    for (int ct = 0; ct < 10; ++ct) bpv[ct] = bp[wc * 160 + ct * 16 + ln];

#pragma unroll
    for (int ri = 0; ri < 8; ++ri) {
        int rt = ri >> 2, r = ri & 3;
        int lrow = wr * 32 + rt * 16 + q * 4 + r;
        const float* pg = gum + (size_t)(rowbase + lrow) * NE + wc * 160 + ln;
        int ybase = lrow * 1280;
        int yswz  = (lrow & 7) << 4;
        float p = 0.f;
#pragma unroll
        for (int ct = 0; ct < 10; ++ct) {
            int col = wc * 160 + ct * 16 + ln;
            float v = acc1[rt][ct][r] + bpv[ct] + pg[ct * 16];
            float e = __expf(v);
            *(unsigned short*)(smem + ybase + ((col * 2) ^ yswz)) = f2b(e);
            p += e;
        }
        p += __shfl_xor(p, 1);
        p += __shfl_xor(p, 2);
        p += __shfl_xor(p, 4);
        p += __shfl_xor(p, 8);
        if (ln == 0) atomicAdd(&sS[lrow], p);
    }
    __syncthreads();   // y + S complete before phase 3 reads

    // ---------------- Phase 3: out = (y @ cb) / S (cb direct from L2, pipelined) ----------------
    f32x4 acc2[2][8];
#pragma unroll
    for (int rt = 0; rt < 2; ++rt)
#pragma unroll
        for (int ct = 0; ct < 8; ++ct) acc2[rt][ct] = fz;

    const int yB = (wr * 32 + ln) * 1280;   // + rt*20480
    bf16x8 yA0, yA1, yB0, yB1;
    {
        const int at = (g * 640 + q * 16) ^ swz;
        yA0 = *(const bf16x8*)(smem + yB + at);
        yA1 = *(const bf16x8*)(smem + yB + 20480 + at);
    }

#pragma unroll 1
    for (int ks2 = 0; ks2 < 10; ks2 += 2) {
        // prefetch ks2+1 into the B set
        {
            const unsigned short* pk = cptr + (ks2 + 1) * 8192;
#pragma unroll
            for (int ct = 0; ct < 8; ++ct) cB[ct] = *(const bf16x8*)(pk + ct * 512);
            const int at = (g * 640 + (ks2 + 1) * 64 + q * 16) ^ swz;
            yB0 = *(const bf16x8*)(smem + yB + at);
            yB1 = *(const bf16x8*)(smem + yB + 20480 + at);
        }
#pragma unroll
        for (int ct = 0; ct < 8; ++ct) {
            MFMA16(acc2[0][ct], yA0, cA[ct]);
            MFMA16(acc2[1][ct], yA1, cA[ct]);
        }
        // prefetch ks2+2 into the A set
        if (ks2 + 2 < 10) {
            const unsigned short* pk = cptr + (ks2 + 2) * 8192;
#pragma unroll
            for (int ct = 0; ct < 8; ++ct) cA[ct] = *(const bf16x8*)(pk + ct * 512);
            const int at = (g * 640 + (ks2 + 2) * 64 + q * 16) ^ swz;
            yA0 = *(const bf16x8*)(smem + yB + at);
            yA1 = *(const bf16x8*)(smem + yB + 20480 + at);
        }
#pragma unroll
        for (int ct = 0; ct < 8; ++ct) {
            MFMA16(acc2[0][ct], yB0, cB[ct]);
            MFMA16(acc2[1][ct], yB1, cB[ct]);
        }
    }

    // epilogue: divide by softmax denom, store fp32
#pragma unroll
    for (int rt = 0; rt < 2; ++rt) {
#pragma unroll
        for (int r = 0; r < 4; ++r) {
            int lrow = wr * 32 + rt * 16 + q * 4 + r;
            float inv = 1.0f / sS[lrow];
            size_t orow = (size_t)(rowbase + lrow) * 512;
#pragma unroll
            for (int ct = 0; ct < 8; ++ct) {
                int col = g * 256 + nb + ct * 16 + ln;
                out[orow + col] = acc2[rt][ct][r] * inv;
            }
        }
    }
}

extern "C" void kernel_launch(void* const* d_in, const int* in_sizes, int n_in,
                              void* d_out, int out_size, void* d_ws, size_t ws_size,
                              hipStream_t stream) {
    const float* x   = (const float*)d_in[0];
    const float* Wp  = (const float*)d_in[1];
    const float* bp  = (const float*)d_in[2];
    const float* cb  = (const float*)d_in[3];
    const float* gum = (const float*)d_in[4];
    float* out = (float*)d_out;

    unsigned short* WpB2 = (unsigned short*)d_ws;
    unsigned short* cbT2 = WpB2 + NE * CIN;

    int prep_total = NE * CIN + 2 * ENTRY * DD;
    prep_kernel<<<(prep_total + 255) / 256, 256, 0, stream>>>(Wp, cb, WpB2, cbT2);

    fused_kernel<<<dim3(BT / MROWS), dim3(TPB), SMEM_BYTES, stream>>>(x, bp, gum, WpB2, cbT2, out);
}